// Round 3
// baseline (3394.313 us; speedup 1.0000x reference)
//
#include <hip/hip_runtime.h>
#include <math.h>

// Problem constants (match reference)
#define B_   32
#define C_   128
#define BCH_ 32
#define DH_  256
#define N_   14400
#define TN   64
#define NT   (N_ / TN)   // 225 exact

// ---------------------------------------------------------------------------
// K1: gather (walk) + conv1 (C=128 -> BCH=32, K=3, SAME) -> flat
// grid (NT, B), block 256.  Thread tile: 2 co x 4 n.
// ---------------------------------------------------------------------------
__global__ __launch_bounds__(256) void k1_gather_conv1(
    const float* __restrict__ latent, const float* __restrict__ w1,
    const float* __restrict__ b1, const int* __restrict__ widx,
    float* __restrict__ flat)
{
    __shared__ float s_x[C_][68];    // seq[t0-1 .. t0+64] (66 used; stride 272B, 16B-aligned)
    __shared__ float s_w[192][34];   // [cil*3+k][co] for current 64-ci group
    __shared__ int   s_idx[66];

    const int t    = threadIdx.x;
    const int tile = blockIdx.x;
    const int b    = blockIdx.y;
    const int t0   = tile * TN;

    if (t < 66) {
        int gn = t0 - 1 + t;
        s_idx[t] = (gn >= 0 && gn < N_) ? widx[gn] : -1;
    }
    __syncthreads();

    // gather seq tile: s_x[ci][pp] = latent[b][ci][widx[t0-1+pp]] (0 if OOB)
    const float* latb = latent + (size_t)b * C_ * N_;
    for (int e = t; e < C_ * 66; e += 256) {
        int ci = e / 66;
        int pp = e - ci * 66;
        int j  = s_idx[pp];
        s_x[ci][pp] = (j >= 0) ? latb[ci * N_ + j] : 0.f;
    }

    const int nb  = t & 15;
    const int cbg = t >> 4;          // 0..15
    const int n0  = nb * 4;
    const int co0 = cbg * 2;

    float acc[2][4];
#pragma unroll
    for (int i = 0; i < 2; ++i) {
        float bv = b1[co0 + i];
#pragma unroll
        for (int j = 0; j < 4; ++j) acc[i][j] = bv;
    }

    for (int cig = 0; cig < 2; ++cig) {
        __syncthreads();
        // stage w1 group: w1[co][cig*64+cil][k] -> s_w[cil*3+k][co]
        for (int e = t; e < 32 * 192; e += 256) {
            int co = e / 192;
            int r  = e - co * 192;   // r = cil*3 + k
            s_w[r][co] = w1[co * (C_ * 3) + cig * 192 + r];
        }
        __syncthreads();

#pragma unroll 8
        for (int cil = 0; cil < 64; ++cil) {
            const int ci = (cig << 6) + cil;
            const float4 xv = *(const float4*)&s_x[ci][n0];
            const float2 xw = *(const float2*)&s_x[ci][n0 + 4];
            const float x[6] = {xv.x, xv.y, xv.z, xv.w, xw.x, xw.y};
#pragma unroll
            for (int k = 0; k < 3; ++k) {
                const float2 wv = *(const float2*)&s_w[cil * 3 + k][co0];
#pragma unroll
                for (int j = 0; j < 4; ++j) {
                    acc[0][j] = fmaf(wv.x, x[j + k], acc[0][j]);
                    acc[1][j] = fmaf(wv.y, x[j + k], acc[1][j]);
                }
            }
        }
    }

    const size_t fb = (size_t)b * BCH_ * N_ + t0 + n0;
#pragma unroll
    for (int i = 0; i < 2; ++i) {
        *(float4*)&flat[fb + (size_t)(co0 + i) * N_] =
            make_float4(acc[i][0], acc[i][1], acc[i][2], acc[i][3]);
    }
}

// ---------------------------------------------------------------------------
// K2: conv2 (32->256) + exact GELU + conv3 (256->128) + spatial_embed
//     + inverse-walk scatter.  hid never hits global memory.
// grid (NT, B), block 256.  Phase B thread tile: 8 co x 4 n.
// ---------------------------------------------------------------------------
__global__ __launch_bounds__(256) void k2_fused(
    const float* __restrict__ flat, const float* __restrict__ w2,
    const float* __restrict__ b2, const float* __restrict__ w3,
    const float* __restrict__ b3, const float* __restrict__ emb,
    const int* __restrict__ widx, float* __restrict__ recon)
{
    __shared__ float s_f[BCH_][72];   // flat[t0-2 .. t0+65] (68 used)
    __shared__ float s_hid[16][68];   // gelu(conv2) for current dh group, pos t0-1 .. t0+64
    __shared__ float s_w3[48][132];   // [dh_l*3+k][co]
    __shared__ int   s_oidx[TN];

    const int t    = threadIdx.x;
    const int tile = blockIdx.x;
    const int b    = blockIdx.y;
    const int t0   = tile * TN;

    if (t < TN) s_oidx[t] = widx[t0 + t];

    // stage flat tile with halo 2 (68 positions)
    const float* fbp = flat + (size_t)b * BCH_ * N_;
    for (int e = t; e < BCH_ * 68; e += 256) {
        int ci = e / 68;
        int pp = e - ci * 68;
        int gn = t0 - 2 + pp;
        s_f[ci][pp] = (gn >= 0 && gn < N_) ? fbp[ci * N_ + gn] : 0.f;
    }

    const int nb  = t & 15;
    const int cb  = t >> 4;          // 0..15
    const int n0  = nb * 4;
    const int co0 = cb * 8;

    float acc[8][4];
#pragma unroll
    for (int i = 0; i < 8; ++i)
#pragma unroll
        for (int j = 0; j < 4; ++j) acc[i][j] = 0.f;

    for (int g = 0; g < 16; ++g) {
        __syncthreads();
        // stage w3 group: w3[co][g*16+dh_l][k] -> s_w3[dh_l*3+k][co]
        for (int e = t; e < C_ * 48; e += 256) {
            int co = e / 48;
            int r  = e - co * 48;
            s_w3[r][co] = w3[co * (DH_ * 3) + g * 48 + r];
        }
        __syncthreads();

        // ---- phase A: hid group = gelu(conv2(flat)), 16 dh x 68 pos, units 1dh x 4pos
        {
            int u = t;
#pragma unroll
            for (int pass = 0; pass < 2; ++pass) {
                if (u < 272) {
                    const int dh  = u / 17;
                    const int q   = u - dh * 17;
                    const int p0  = q * 4;
                    const int dhg = (g << 4) + dh;
                    const float* wrow = w2 + dhg * (BCH_ * 3);
                    float a0, a1, a2, a3;
                    a0 = a1 = a2 = a3 = b2[dhg];
#pragma unroll 8
                    for (int ci = 0; ci < BCH_; ++ci) {
                        const float4 xv = *(const float4*)&s_f[ci][p0];
                        const float2 xw = *(const float2*)&s_f[ci][p0 + 4];
                        const float x[6] = {xv.x, xv.y, xv.z, xv.w, xw.x, xw.y};
                        const float wk0 = wrow[ci * 3 + 0];
                        const float wk1 = wrow[ci * 3 + 1];
                        const float wk2 = wrow[ci * 3 + 2];
                        a0 = fmaf(wk0, x[0], fmaf(wk1, x[1], fmaf(wk2, x[2], a0)));
                        a1 = fmaf(wk0, x[1], fmaf(wk1, x[2], fmaf(wk2, x[3], a1)));
                        a2 = fmaf(wk0, x[2], fmaf(wk1, x[3], fmaf(wk2, x[4], a2)));
                        a3 = fmaf(wk0, x[3], fmaf(wk1, x[4], fmaf(wk2, x[5], a3)));
                    }
                    const float rs2 = 0.7071067811865476f;
                    float4 hv;
                    hv.x = 0.5f * a0 * (1.f + erff(a0 * rs2));
                    hv.y = 0.5f * a1 * (1.f + erff(a1 * rs2));
                    hv.z = 0.5f * a2 * (1.f + erff(a2 * rs2));
                    hv.w = 0.5f * a3 * (1.f + erff(a3 * rs2));
                    // SAME-padding fix: hid outside [0,N) must be ZERO for conv3,
                    // not gelu(conv2(zero-padded flat)).  s_hid[dh][p] = hid(t0-1+p).
                    const int gh = t0 - 1 + p0;
                    if (gh + 0 < 0 || gh + 0 >= N_) hv.x = 0.f;
                    if (gh + 1 < 0 || gh + 1 >= N_) hv.y = 0.f;
                    if (gh + 2 < 0 || gh + 2 >= N_) hv.z = 0.f;
                    if (gh + 3 < 0 || gh + 3 >= N_) hv.w = 0.f;
                    *(float4*)&s_hid[dh][p0] = hv;
                }
                u = t + 256;  // second pass unit
            }
        }
        __syncthreads();

        // ---- phase B: conv3 partial accumulation over this dh group
#pragma unroll
        for (int dh = 0; dh < 16; ++dh) {
            const float4 xv = *(const float4*)&s_hid[dh][n0];
            const float2 xw = *(const float2*)&s_hid[dh][n0 + 4];
            const float x[6] = {xv.x, xv.y, xv.z, xv.w, xw.x, xw.y};
#pragma unroll
            for (int k = 0; k < 3; ++k) {
                const float4 wa = *(const float4*)&s_w3[dh * 3 + k][co0];
                const float4 wb = *(const float4*)&s_w3[dh * 3 + k][co0 + 4];
#pragma unroll
                for (int j = 0; j < 4; ++j) {
                    const float xj = x[j + k];
                    acc[0][j] = fmaf(wa.x, xj, acc[0][j]);
                    acc[1][j] = fmaf(wa.y, xj, acc[1][j]);
                    acc[2][j] = fmaf(wa.z, xj, acc[2][j]);
                    acc[3][j] = fmaf(wa.w, xj, acc[3][j]);
                    acc[4][j] = fmaf(wb.x, xj, acc[4][j]);
                    acc[5][j] = fmaf(wb.y, xj, acc[5][j]);
                    acc[6][j] = fmaf(wb.z, xj, acc[6][j]);
                    acc[7][j] = fmaf(wb.w, xj, acc[7][j]);
                }
            }
        }
    }

    // epilogue: bias + spatial embed (walked space) + scatter via walk_idx
    const size_t rb = (size_t)b * C_ * N_;
#pragma unroll
    for (int i = 0; i < 8; ++i) {
        const int co = co0 + i;
        const float bias = b3[co];
        const float4 ev = *(const float4*)&emb[(size_t)co * N_ + t0 + n0];
        const float e4[4] = {ev.x, ev.y, ev.z, ev.w};
#pragma unroll
        for (int j = 0; j < 4; ++j) {
            recon[rb + (size_t)co * N_ + s_oidx[n0 + j]] = acc[i][j] + bias + e4[j];
        }
    }
}

// ---------------------------------------------------------------------------
extern "C" void kernel_launch(void* const* d_in, const int* in_sizes, int n_in,
                              void* d_out, int out_size, void* d_ws, size_t ws_size,
                              hipStream_t stream)
{
    const float* latent = (const float*)d_in[0];
    const float* w1     = (const float*)d_in[1];
    const float* b1     = (const float*)d_in[2];
    const float* w2     = (const float*)d_in[3];
    const float* b2     = (const float*)d_in[4];
    const float* w3     = (const float*)d_in[5];
    const float* b3     = (const float*)d_in[6];
    const float* emb    = (const float*)d_in[7];
    const int*   widx   = (const int*)d_in[8];

    float* recon = (float*)d_out;                       // B*C*N
    float* flat  = recon + (size_t)B_ * C_ * N_;        // B*BCH*N (second tuple output)

    dim3 grid(NT, B_);
    k1_gather_conv1<<<grid, 256, 0, stream>>>(latent, w1, b1, widx, flat);
    k2_fused<<<grid, 256, 0, stream>>>(flat, w2, b2, w3, b3, emb, widx, recon);
}